// Round 1
// baseline (616.591 us; speedup 1.0000x reference)
//
#include <hip/hip_runtime.h>

#define EPS 1e-8f

constexpr int B = 16, C = 19, H = 512, W = 512;
constexpr int HW = H * W;               // 262144
constexpr int NPIX = B * HW;            // 4194304
constexpr long long NPRED = (long long)B * C * HW;  // 79691776

// ws layout (floats): [0..360] ncm (row-major [c][t]), [361..721] log(ncm+eps), [768] loss accumulator

__global__ void ncm_kernel(const float* __restrict__ cm, float* __restrict__ ws) {
    int t = threadIdx.x;
    if (t == 0) ws[768] = 0.0f;  // zero the loss accumulator (ws is poisoned each call)
    if (t < C) {
        float row[C];
        float m = -1e30f;
        #pragma unroll
        for (int j = 0; j < C; ++j) { row[j] = cm[t * C + j]; m = fmaxf(m, row[j]); }
        float s = 0.0f;
        #pragma unroll
        for (int j = 0; j < C; ++j) { row[j] = __expf(row[j] - m); s += row[j]; }
        float inv = 1.0f / s;
        #pragma unroll
        for (int j = 0; j < C; ++j) {
            float v = row[j] * inv;
            ws[t * C + j] = v;
            ws[361 + t * C + j] = __logf(v + EPS);
        }
    }
}

__global__ __launch_bounds__(256) void emloss_main(
        const float* __restrict__ logits,
        const int* __restrict__ targets,
        const float* __restrict__ ws,
        float* __restrict__ pred,
        float* __restrict__ loss_acc) {
    __shared__ float s_ncm[C * C];
    __shared__ float s_lpre[C * C];
    for (int i = threadIdx.x; i < C * C; i += blockDim.x) {
        s_ncm[i]  = ws[i];
        s_lpre[i] = ws[361 + i];
    }
    __syncthreads();

    int g = blockIdx.x * blockDim.x + threadIdx.x;  // one group of 4 consecutive pixels
    int pbase = g * 4;                               // < NPIX, grid exactly covers
    int b = pbase / HW;
    int r = pbase - b * HW;                          // multiple of 4 (HW % 4 == 0)
    const float* lp = logits + (size_t)b * C * HW + r;
    float*       op = pred   + (size_t)b * C * HW + r;

    // load 19 classes x 4 pixels into registers, coalesced float4 per class
    float xs[C][4];
    #pragma unroll
    for (int c = 0; c < C; ++c) {
        float4 v = *(const float4*)(lp + (size_t)c * HW);
        xs[c][0] = v.x; xs[c][1] = v.y; xs[c][2] = v.z; xs[c][3] = v.w;
    }
    int4 tv = *(const int4*)(targets + pbase);
    int tt[4] = {tv.x, tv.y, tv.z, tv.w};

    // softmax per pixel: max, exp-in-place, sum
    float inv_s[4];
    #pragma unroll
    for (int k = 0; k < 4; ++k) {
        float m = -1e30f;
        #pragma unroll
        for (int c = 0; c < C; ++c) m = fmaxf(m, xs[c][k]);
        float s = 0.0f;
        #pragma unroll
        for (int c = 0; c < C; ++c) {
            float e = __expf(xs[c][k] - m);
            xs[c][k] = e;
            s += e;
        }
        inv_s[k] = 1.0f / s;
    }

    // fused pred store + loss:
    //   q_c = num_c / denom,  num_c = ncm[c][t] * pred_c,  denom = sum_c num_c
    //   loss = sum_c q_c * (lpre[c][t] + log(pred_c+eps)) = (sum num*term)/denom
    float denom[4] = {0, 0, 0, 0};
    float wsum[4]  = {0, 0, 0, 0};
    #pragma unroll
    for (int c = 0; c < C; ++c) {
        float pk[4];
        #pragma unroll
        for (int k = 0; k < 4; ++k) {
            float p = xs[c][k] * inv_s[k];
            pk[k] = p;
            float nm  = s_ncm[c * C + tt[k]];
            float num = nm * p;
            denom[k] += num;
            wsum[k]  += num * (s_lpre[c * C + tt[k]] + __logf(p + EPS));
        }
        float4 pv = make_float4(pk[0], pk[1], pk[2], pk[3]);
        *(float4*)(op + (size_t)c * HW) = pv;
    }

    float lsum = 0.0f;
    #pragma unroll
    for (int k = 0; k < 4; ++k) lsum += wsum[k] / denom[k];

    // wave-64 shuffle reduction, one atomic per wave
    #pragma unroll
    for (int off = 32; off > 0; off >>= 1) lsum += __shfl_down(lsum, off);
    if ((threadIdx.x & 63) == 0) atomicAdd(loss_acc, lsum);
}

__global__ void finalize_kernel(const float* __restrict__ acc, float* __restrict__ out) {
    out[0] = -acc[0] / (float)NPIX;
}

extern "C" void kernel_launch(void* const* d_in, const int* in_sizes, int n_in,
                              void* d_out, int out_size, void* d_ws, size_t ws_size,
                              hipStream_t stream) {
    const float* logits  = (const float*)d_in[0];
    const int*   targets = (const int*)d_in[1];
    const float* cm      = (const float*)d_in[2];
    float* out = (float*)d_out;
    float* ws  = (float*)d_ws;

    hipLaunchKernelGGL(ncm_kernel, dim3(1), dim3(64), 0, stream, cm, ws);

    int groups = NPIX / 4;            // 1048576
    int block = 256;
    int grid = groups / block;        // 4096
    hipLaunchKernelGGL(emloss_main, dim3(grid), dim3(block), 0, stream,
                       logits, targets, ws, out, ws + 768);

    hipLaunchKernelGGL(finalize_kernel, dim3(1), dim3(1), 0, stream,
                       ws + 768, out + NPRED);
}